// Round 5
// baseline (419.579 us; speedup 1.0000x reference)
//
#include <hip/hip_runtime.h>

// Problem constants
constexpr int kB  = 16;    // batch
constexpr int kN  = 1024;  // route nodes
constexpr int kCI = 64;    // in caps dim
constexpr int kC  = 32;    // out capsules
constexpr int kO  = 32;    // out dim
constexpr int kNT = 32;    // n per block in priors kernel
constexpr int kIC = 16;    // i-chunk size for x staging
constexpr int XSS = 260;   // xs floats per n-row (16*16=256, +4 pad: keeps
                           // 16B alignment for b128 AND spreads banks 4*nl)

// priors fp32: element (c,n,b,o) at (c*kN+n)*nstride + b*kO + o.
// nstride=512 (dense in d_ws) or 2048 (in-place over consumed rw rows).

// ---------------------------------------------------------------------------
// Kernel 1: priors(c,n,b,o) = sum_i x[b][n][i] * rw[c][n][i][o]   (all fp32)
// 1024 blocks (32 c x 32 n-tiles) x 256 threads. Thread = (og = t&7, nl = t>>3):
// owns (n = n0+nl, o = og*4..og*4+3), accumulates acc[16 b][4 o].
// rw is streamed global->register float4 per i (each element read exactly
// once by exactly one thread; 8 og-lanes cover full 128B lines); only x is
// staged in LDS, transposed to [nl][i][b] so compute reads are ds_read_b128.
// In-place mode: rw row n's front 2 KB is read only by this block's 8
// (nl, og) lanes, each of which finishes all its reads (i-loop) before its
// own epilogue store — per-thread program order makes the overwrite safe.
// ---------------------------------------------------------------------------
__global__ __launch_bounds__(256, 4) void priors_kernel(
    const float* __restrict__ x,     // fp32 [B][N][CI]
    const float* rw,                 // fp32 [C][N][CI][O]   (may alias priors)
    float* priors, int nstride) {
  const int c  = blockIdx.x >> 5;
  const int n0 = (blockIdx.x & 31) * kNT;
  const int t  = threadIdx.x;
  const int og = t & 7;
  const int nl = t >> 3;

  __shared__ float xs[kNT * XSS];    // ~33 KB

  float acc[kB][4];
  #pragma unroll
  for (int b = 0; b < kB; ++b)
    #pragma unroll
    for (int o = 0; o < 4; ++o) acc[b][o] = 0.f;

  const float* rwp = rw + (size_t)(c * kN + n0 + nl) * (kCI * kO) + og * 4;

  for (int ch = 0; ch < kCI / kIC; ++ch) {
    const int i0 = ch * kIC;
    if (ch) __syncthreads();         // xs reuse: previous chunk's reads done
    // stage x chunk: 32 n x 16 i x 16 b floats, transposed to [nl][i][b]
    #pragma unroll
    for (int it = 0; it < 8; ++it) {
      int f  = it * 256 + t;         // 0..2047 float4s
      int ii = f & 3;                // i sub-quad
      int nn = (f >> 2) & 31;
      int b  = f >> 7;               // 0..15
      float4 v = *(const float4*)(x + (size_t)(b * kN + n0 + nn) * kCI + i0 + ii * 4);
      float* d = xs + nn * XSS + (ii * 4) * kB + b;
      d[0]  = v.x;
      d[16] = v.y;
      d[32] = v.z;
      d[48] = v.w;
    }
    __syncthreads();
    // compute over this i-chunk
    #pragma unroll
    for (int il = 0; il < kIC; ++il) {
      const int i = i0 + il;
      float4 w = *(const float4*)(rwp + (size_t)i * kO);
      const float* xp = xs + nl * XSS + il * kB;
      float4 xb[4];
      #pragma unroll
      for (int q = 0; q < 4; ++q) xb[q] = *(const float4*)(xp + q * 4);
      const float* xf = (const float*)xb;
      #pragma unroll
      for (int b = 0; b < kB; ++b) {
        const float xv = xf[b];
        acc[b][0] += xv * w.x;
        acc[b][1] += xv * w.y;
        acc[b][2] += xv * w.z;
        acc[b][3] += xv * w.w;
      }
    }
  }

  // epilogue: fp32 float4 stores (8 og-lanes -> 128B contiguous per (n,b))
  float* dst = priors + (size_t)(c * kN + n0 + nl) * nstride + og * 4;
  #pragma unroll
  for (int b = 0; b < kB; ++b) {
    float4 v = make_float4(acc[b][0], acc[b][1], acc[b][2], acc[b][3]);
    *(float4*)(dst + (size_t)b * kO) = v;
  }
}

// ---------------------------------------------------------------------------
// Kernel 2: per (c,b), 3 routing iterations entirely on-chip.
// Each thread holds 4 prior rows (n = t, t+256, t+512, t+768) in registers.
// grid = C*B = 512 blocks, 256 threads.
// ---------------------------------------------------------------------------
__global__ __launch_bounds__(256) void routing_kernel(
    const float* priors, int nstride,
    float* __restrict__ out) {               // fp32 [C][B][O]
  const int cb = blockIdx.x;
  const int c = cb >> 4, b = cb & 15;
  const int t = threadIdx.x;

  __shared__ float R[256 * 33];              // vector-reduce scratch
  __shared__ float S2[8 * 33];
  __shared__ float out_lds[kO];
  __shared__ float wred[8];                  // [0..3]=max partials, [4..7]=den partials

  const float* base = priors + (size_t)c * kN * nstride + b * kO;

  float p[4][kO];
  #pragma unroll
  for (int k = 0; k < 4; ++k) {
    const float* rp = base + (size_t)(t + 256 * k) * nstride;
    #pragma unroll
    for (int q = 0; q < 8; ++q) {
      float4 v = *(const float4*)(rp + q * 4);
      p[k][q * 4 + 0] = v.x; p[k][q * 4 + 1] = v.y;
      p[k][q * 4 + 2] = v.z; p[k][q * 4 + 3] = v.w;
    }
  }

  float l[4] = {0.f, 0.f, 0.f, 0.f};

  for (int iter = 0; iter < 3; ++iter) {
    // logits += priors . out_prev   (skipped on iter 0: logits stay 0)
    if (iter > 0) {
      #pragma unroll
      for (int k = 0; k < 4; ++k) {
        float d = 0.f;
        #pragma unroll
        for (int o = 0; o < kO; ++o) d += p[k][o] * out_lds[o];
        l[k] += d;
      }
    }
    // block max over 1024 logits
    float lm = fmaxf(fmaxf(l[0], l[1]), fmaxf(l[2], l[3]));
    #pragma unroll
    for (int s = 32; s >= 1; s >>= 1) lm = fmaxf(lm, __shfl_xor(lm, s));
    if ((t & 63) == 0) wred[t >> 6] = lm;
    __syncthreads();
    const float m = fmaxf(fmaxf(wred[0], wred[1]), fmaxf(wred[2], wred[3]));

    // weighted accumulation (unnormalized softmax)
    float acc[kO];
    #pragma unroll
    for (int o = 0; o < kO; ++o) acc[o] = 0.f;
    float denp = 0.f;
    #pragma unroll
    for (int k = 0; k < 4; ++k) {
      float e = __expf(l[k] - m);
      denp += e;
      #pragma unroll
      for (int o = 0; o < kO; ++o) acc[o] += e * p[k][o];
    }
    #pragma unroll
    for (int s = 32; s >= 1; s >>= 1) denp += __shfl_xor(denp, s);
    if ((t & 63) == 0) wred[4 + (t >> 6)] = denp;

    // block-reduce the 32-vector acc
    #pragma unroll
    for (int o = 0; o < kO; ++o) R[t * 33 + o] = acc[o];
    __syncthreads();
    {
      int o = t & 31, g = t >> 5;
      float s = 0.f;
      #pragma unroll
      for (int jj = 0; jj < 32; ++jj) s += R[(g * 32 + jj) * 33 + o];
      S2[g * 33 + o] = s;
    }
    __syncthreads();
    if (t < kO) {
      float s = 0.f;
      #pragma unroll
      for (int g = 0; g < 8; ++g) s += S2[g * 33 + t];
      const float den = wred[4] + wred[5] + wred[6] + wred[7];
      s /= den;
      // squash across the 32 lanes holding s[o]
      float sq = s * s;
      #pragma unroll
      for (int sh = 16; sh >= 1; sh >>= 1) sq += __shfl_xor(sq, sh);
      const float r = sqrtf(sq);
      const float ov = s * (r / (1.f + sq));
      out_lds[t] = ov;
      if (iter == 2) out[cb * kO + t] = ov;
    }
    __syncthreads();
  }
}

extern "C" void kernel_launch(void* const* d_in, const int* in_sizes, int n_in,
                              void* d_out, int out_size, void* d_ws, size_t ws_size,
                              hipStream_t stream) {
  const float* x  = (const float*)d_in[0];   // fp32 [B][N][CI]
  const float* rw = (const float*)d_in[1];   // fp32 [C][N][CI][O]
  float* out = (float*)d_out;                // fp32 [C][B][1][1][O]

  // fp32 priors scratch: 64 MB dense in d_ws; fallback: in-place over rw
  // (per-n 8 KB rw row fully consumed before its front 2 KB is overwritten).
  const size_t need = (size_t)kC * kN * kB * kO * sizeof(float); // 64 MB
  float* priors;
  int nstride;
  if (ws_size >= need) {
    priors  = (float*)d_ws;
    nstride = kB * kO;            // 512 floats per n-row (dense)
  } else {
    priors  = (float*)const_cast<float*>(rw);
    nstride = kCI * kO;           // 2048 floats per n-row (in-place)
  }

  priors_kernel<<<dim3(kC * (kN / kNT)), dim3(256), 0, stream>>>(x, rw, priors, nstride);
  routing_kernel<<<dim3(kC * kB), dim3(256), 0, stream>>>(priors, nstride, out);
}